// Round 1
// 142.953 us; speedup vs baseline: 1.1045x; 1.1045x over previous
//
#include <hip/hip_runtime.h>

#define C 128        // IN_CH == OUT_CH
#define NPB 16       // nodes per node-pre block
#define CAP 128      // per-node bucket capacity (mean deg 64, 8 sigma; overflow path exists)
#define OVF_MAX 65536
#define EPT1 16      // edges per thread in partition kernel (block covers 4096 edges)
#define GSH 5        // log2(nodes per bin)
#define G (1 << GSH) // 32 nodes per bin
#define CAPB 3072    // bin capacity in entries (mean ~2045 + 64B-pad overhead + 8 sigma)
#define MAXBIN 512   // static LDS sizing; requires N <= MAXBIN*G (=16384)

__device__ __forceinline__ unsigned bf16_bits(float x) {   // round-to-nearest-even
    unsigned u = __float_as_uint(x);
    u += 0x7FFFu + ((u >> 16) & 1u);
    return u >> 16;
}
__device__ __forceinline__ float bf16f(unsigned short b) {
    return __uint_as_float(((unsigned)b) << 16);
}

// Heterogeneous kernel: blocks [0, PBLK) partition edges into coarse bins (32
// nodes/bin) with LDS histograms + 64B-aligned per-block runs (coalesced,
// XCD-private line ownership -> no partial-line write amplification).
// Blocks [PBLK, PBLK+PB) compute P = x@W1[:C] (bf16), Q = x@W1[C:] (fp32).
__global__ void fused_pre_kernel(const float* __restrict__ x, const float* __restrict__ W1,
                                 unsigned short* __restrict__ P16, float* __restrict__ Q,
                                 const int* __restrict__ ei, const float* __restrict__ attr,
                                 uint2* __restrict__ bins, int* __restrict__ bin_cursor,
                                 int* __restrict__ ovf_cnt, int2* __restrict__ ovf,
                                 int N, int E, int PBLK, int NBIN) {
    if ((int)blockIdx.x < PBLK) {
        __shared__ int hist[MAXBIN];   // pass1: counts; after reserve: global run base
        __shared__ int boff[MAXBIN];   // pass2: running offset within this block's run
        for (int i = threadIdx.x; i < NBIN; i += 256) { hist[i] = 0; boff[i] = 0; }
        __syncthreads();
        const int base = ((int)blockIdx.x * 256 + (int)threadIdx.x) * EPT1;
        const int rem = (base < E) ? min(EPT1, E - base) : 0;
        const bool vec = (rem == EPT1) && ((E & 3) == 0);
        // ---- pass 1: LDS histogram of destination bins ----
        if (vec) {
#pragma unroll
            for (int j0 = 0; j0 < EPT1; j0 += 4) {
                const int4 c = *(const int4*)(ei + (size_t)E + base + j0);
                atomicAdd(&hist[c.x >> GSH], 1);
                atomicAdd(&hist[c.y >> GSH], 1);
                atomicAdd(&hist[c.z >> GSH], 1);
                atomicAdd(&hist[c.w >> GSH], 1);
            }
        } else {
            for (int j = 0; j < rem; ++j)
                atomicAdd(&hist[ei[(size_t)E + base + j] >> GSH], 1);
        }
        __syncthreads();
        // ---- reserve a 64B-aligned run per bin; sentinel-fill the pad ----
        for (int i = threadIdx.x; i < NBIN; i += 256) {
            const int c = hist[i];
            int b = 0;
            if (c) {
                const int cp = (c + 7) & ~7;           // pad to 8 entries = 64B
                b = atomicAdd(&bin_cursor[i], cp);
                for (int k = c; k < cp; ++k)
                    if (b + k < CAPB)
                        bins[(size_t)i * CAPB + b + k] = make_uint2(0u, 0xFFFFFFFFu);
            }
            hist[i] = b;                               // repurpose as run base
        }
        __syncthreads();
        // ---- pass 2: place edges into the block's private runs ----
        if (vec) {
#pragma unroll
            for (int j0 = 0; j0 < EPT1; j0 += 4) {
                const int4 r = *(const int4*)(ei + base + j0);
                const int4 c = *(const int4*)(ei + (size_t)E + base + j0);
                const float4 a = *(const float4*)(attr + base + j0);
                const int rr[4] = {r.x, r.y, r.z, r.w};
                const int cc[4] = {c.x, c.y, c.z, c.w};
                const float aa[4] = {a.x, a.y, a.z, a.w};
#pragma unroll
                for (int j = 0; j < 4; ++j) {
                    const int bin = cc[j] >> GSH;
                    const int idx = hist[bin] + atomicAdd(&boff[bin], 1);
                    const unsigned pk = (bf16_bits(aa[j]) << 16) | (unsigned)rr[j];
                    if (idx < CAPB) {
                        bins[(size_t)bin * CAPB + idx] = make_uint2(pk, (unsigned)cc[j]);
                    } else {
                        const int o = atomicAdd(ovf_cnt, 1);
                        if (o < OVF_MAX) ovf[o] = make_int2(cc[j], (int)pk);
                    }
                }
            }
        } else {
            for (int j = 0; j < rem; ++j) {
                const int row = ei[base + j], colv = ei[(size_t)E + base + j];
                const int bin = colv >> GSH;
                const int idx = hist[bin] + atomicAdd(&boff[bin], 1);
                const unsigned pk = (bf16_bits(attr[base + j]) << 16) | (unsigned)row;
                if (idx < CAPB) {
                    bins[(size_t)bin * CAPB + idx] = make_uint2(pk, (unsigned)colv);
                } else {
                    const int o = atomicAdd(ovf_cnt, 1);
                    if (o < OVF_MAX) ovf[o] = make_int2(colv, (int)pk);
                }
            }
        }
    } else {
        // node pre-GEMM: 16 nodes/block, 256 threads (half -> P bf16, half -> Q fp32)
        __shared__ float xs[NPB][C];
        const int pb = (int)blockIdx.x - PBLK;
        const int n0 = pb * NPB;
        const int tt = threadIdx.x & (C - 1);
        const int half = threadIdx.x >> 7;
        for (int i = threadIdx.x; i < NPB * C; i += 256) {
            const int gi = n0 * C + i;
            xs[0][i] = (gi < N * C) ? x[gi] : 0.f;
        }
        __syncthreads();
        const float* __restrict__ Wb = W1 + (half ? (C * C) : 0) + tt;
        float acc[NPB] = {};
        for (int k = 0; k < C; ++k) {
            const float w = Wb[k * C];
#pragma unroll
            for (int j = 0; j < NPB; ++j)
                acc[j] = fmaf(xs[j][k], w, acc[j]);
        }
#pragma unroll
        for (int j = 0; j < NPB; ++j)
            if (n0 + j < N) {
                if (half) Q[(size_t)(n0 + j) * C + tt] = acc[j];
                else      P16[(size_t)(n0 + j) * C + tt] = (unsigned short)bf16_bits(acc[j]);
            }
    }
}

// Level-2 scatter: one block per bin. Reads the bin's entries (coalesced),
// places them into exact per-node buckets via LDS position counters. The 4B
// scattered writes land in a 16KB region owned by this block -> L2-resident,
// full-line evictions. Writes exact per-node counts into cursor (no memset).
__global__ void bin_scatter_kernel(const uint2* __restrict__ bins, const int* __restrict__ bin_cursor,
                                   unsigned* __restrict__ sorted, int* __restrict__ cursor,
                                   int* __restrict__ ovf_cnt, int2* __restrict__ ovf, int N) {
    __shared__ int off[G];
    const int b = blockIdx.x;
    const int n0 = b << GSH;
    if (threadIdx.x < G) off[threadIdx.x] = 0;
    __syncthreads();
    const int cnt = min(bin_cursor[b], CAPB);
    const uint2* __restrict__ src = bins + (size_t)b * CAPB;
    for (int i = threadIdx.x; i < cnt; i += 256) {
        const uint2 e = src[i];
        const unsigned noff = e.y - (unsigned)n0;
        if (noff < (unsigned)G) {                      // skip pad sentinels
            const int pos = atomicAdd(&off[noff], 1);
            if (pos < CAP) {
                sorted[(size_t)e.y * CAP + pos] = e.x;
            } else {
                const int o = atomicAdd(ovf_cnt, 1);
                if (o < OVF_MAX) ovf[o] = make_int2((int)e.y, (int)e.x);
            }
        }
    }
    __syncthreads();
    if (threadIdx.x < G && n0 + (int)threadIdx.x < N)
        cursor[n0 + threadIdx.x] = min(off[threadIdx.x], CAP);
}

// Fused aggregation + output GEMM. 2 nodes per 256-thread block.
// Thread (j = t>>7, slice = (t>>5)&3, ch4 = t&31): slice-parallel over edges,
// lane owns 4 channels via ushort4 bf16 gathers of P. LDS-reduce slices -> H,
// then k-sliced W2 matmul with float4 loads, LDS-reduce -> out.
__global__ void agg_out_kernel(const unsigned* __restrict__ sorted, const int* __restrict__ cursor,
                               const unsigned short* __restrict__ P16, const float* __restrict__ Q,
                               const float* __restrict__ b1, const float* __restrict__ W2,
                               const float* __restrict__ b2,
                               const int* __restrict__ ovf_cnt, const int2* __restrict__ ovf,
                               float* __restrict__ out, int N) {
    __shared__ float4 part[2][4][32];
    __shared__ float hs[2][C];
    const int t = threadIdx.x;
    const int j = t >> 7;
    const int slice = (t >> 5) & 3;
    const int ch4 = t & 31;
    const int n = blockIdx.x * 2 + j;

    float4 acc = make_float4(0.f, 0.f, 0.f, 0.f);
    float4 qb = acc;
    int deg = 0;
    int mcnt = 0;   // overflow edges matched to this node (corrects deg for b2)
    if (n < N) {
        deg = cursor[n];
        const float4 q4  = *(const float4*)(Q + (size_t)n * C + (ch4 << 2));
        const float4 b14 = *(const float4*)(b1 + (ch4 << 2));
        qb = make_float4(q4.x + b14.x, q4.y + b14.y, q4.z + b14.z, q4.w + b14.w);
        const int cnt = min(deg, CAP);
        const unsigned* __restrict__ buf = sorted + (size_t)n * CAP;
        const int chunk = (cnt + 3) >> 2;
        const int s0 = min(slice * chunk, cnt);
        const int s1 = min(s0 + chunk, cnt);
        int i = s0;
        for (; i + 4 <= s1; i += 4) {
            const unsigned v0 = buf[i], v1 = buf[i + 1], v2 = buf[i + 2], v3 = buf[i + 3];
            const ushort4 p0 = *(const ushort4*)(P16 + (((size_t)(v0 & 0xFFFFu)) << 7) + (ch4 << 2));
            const ushort4 p1 = *(const ushort4*)(P16 + (((size_t)(v1 & 0xFFFFu)) << 7) + (ch4 << 2));
            const ushort4 p2 = *(const ushort4*)(P16 + (((size_t)(v2 & 0xFFFFu)) << 7) + (ch4 << 2));
            const ushort4 p3 = *(const ushort4*)(P16 + (((size_t)(v3 & 0xFFFFu)) << 7) + (ch4 << 2));
            const float a0 = __uint_as_float(v0 & 0xFFFF0000u);
            const float a1 = __uint_as_float(v1 & 0xFFFF0000u);
            const float a2 = __uint_as_float(v2 & 0xFFFF0000u);
            const float a3 = __uint_as_float(v3 & 0xFFFF0000u);
            acc.x += fmaxf(fmaf(a0, bf16f(p0.x), qb.x), 0.f) + fmaxf(fmaf(a1, bf16f(p1.x), qb.x), 0.f)
                   + fmaxf(fmaf(a2, bf16f(p2.x), qb.x), 0.f) + fmaxf(fmaf(a3, bf16f(p3.x), qb.x), 0.f);
            acc.y += fmaxf(fmaf(a0, bf16f(p0.y), qb.y), 0.f) + fmaxf(fmaf(a1, bf16f(p1.y), qb.y), 0.f)
                   + fmaxf(fmaf(a2, bf16f(p2.y), qb.y), 0.f) + fmaxf(fmaf(a3, bf16f(p3.y), qb.y), 0.f);
            acc.z += fmaxf(fmaf(a0, bf16f(p0.z), qb.z), 0.f) + fmaxf(fmaf(a1, bf16f(p1.z), qb.z), 0.f)
                   + fmaxf(fmaf(a2, bf16f(p2.z), qb.z), 0.f) + fmaxf(fmaf(a3, bf16f(p3.z), qb.z), 0.f);
            acc.w += fmaxf(fmaf(a0, bf16f(p0.w), qb.w), 0.f) + fmaxf(fmaf(a1, bf16f(p1.w), qb.w), 0.f)
                   + fmaxf(fmaf(a2, bf16f(p2.w), qb.w), 0.f) + fmaxf(fmaf(a3, bf16f(p3.w), qb.w), 0.f);
        }
        for (; i < s1; ++i) {
            const unsigned v = buf[i];
            const ushort4 p = *(const ushort4*)(P16 + (((size_t)(v & 0xFFFFu)) << 7) + (ch4 << 2));
            const float a = __uint_as_float(v & 0xFFFF0000u);
            acc.x += fmaxf(fmaf(a, bf16f(p.x), qb.x), 0.f);
            acc.y += fmaxf(fmaf(a, bf16f(p.y), qb.y), 0.f);
            acc.z += fmaxf(fmaf(a, bf16f(p.z), qb.z), 0.f);
            acc.w += fmaxf(fmaf(a, bf16f(p.w), qb.w), 0.f);
        }
        if (slice == 0) {   // overflow entries (essentially never populated)
            const int oc = min(*ovf_cnt, OVF_MAX);
            for (int o = 0; o < oc; ++o) {
                const int2 v = ovf[o];
                if (v.x == n) {
                    ++mcnt;
                    const unsigned u = (unsigned)v.y;
                    const ushort4 p = *(const ushort4*)(P16 + (((size_t)(u & 0xFFFFu)) << 7) + (ch4 << 2));
                    const float a = __uint_as_float(u & 0xFFFF0000u);
                    acc.x += fmaxf(fmaf(a, bf16f(p.x), qb.x), 0.f);
                    acc.y += fmaxf(fmaf(a, bf16f(p.y), qb.y), 0.f);
                    acc.z += fmaxf(fmaf(a, bf16f(p.z), qb.z), 0.f);
                    acc.w += fmaxf(fmaf(a, bf16f(p.w), qb.w), 0.f);
                }
            }
        }
    }
    part[j][slice][ch4] = acc;
    __syncthreads();
    if (slice == 0 && n < N) {
        const float4 r0 = part[j][0][ch4], r1 = part[j][1][ch4];
        const float4 r2 = part[j][2][ch4], r3 = part[j][3][ch4];
        float4 h;
        h.x = r0.x + r1.x + r2.x + r3.x;
        h.y = r0.y + r1.y + r2.y + r3.y;
        h.z = r0.z + r1.z + r2.z + r3.z;
        h.w = r0.w + r1.w + r2.w + r3.w;
        *(float4*)(&hs[j][ch4 << 2]) = h;
    }
    __syncthreads();
    // k-sliced matmul: slice covers k in [slice*32, slice*32+32)
    float4 o = make_float4(0.f, 0.f, 0.f, 0.f);
    if (n < N) {
        const int k0 = slice << 5;
#pragma unroll 8
        for (int k = k0; k < k0 + 32; ++k) {
            const float hv = hs[j][k];
            const float4 w = *(const float4*)(W2 + (size_t)k * C + (ch4 << 2));
            o.x = fmaf(hv, w.x, o.x);
            o.y = fmaf(hv, w.y, o.y);
            o.z = fmaf(hv, w.z, o.z);
            o.w = fmaf(hv, w.w, o.w);
        }
    }
    __syncthreads();            // before reusing `part`
    part[j][slice][ch4] = o;
    __syncthreads();
    if (slice == 0 && n < N) {
        const float4 r0 = part[j][0][ch4], r1 = part[j][1][ch4];
        const float4 r2 = part[j][2][ch4], r3 = part[j][3][ch4];
        const float4 b24 = *(const float4*)(b2 + (ch4 << 2));
        const float d = (float)(deg + mcnt);
        float4 res;
        res.x = fmaf(d, b24.x, r0.x + r1.x + r2.x + r3.x);
        res.y = fmaf(d, b24.y, r0.y + r1.y + r2.y + r3.y);
        res.z = fmaf(d, b24.z, r0.z + r1.z + r2.z + r3.z);
        res.w = fmaf(d, b24.w, r0.w + r1.w + r2.w + r3.w);
        *(float4*)(out + (size_t)n * C + (ch4 << 2)) = res;
    }
}

extern "C" void kernel_launch(void* const* d_in, const int* in_sizes, int n_in,
                              void* d_out, int out_size, void* d_ws, size_t ws_size,
                              hipStream_t stream) {
    const float* x    = (const float*)d_in[0];
    const int*   ei   = (const int*)d_in[1];
    const float* attr = (const float*)d_in[2];
    const float* W1   = (const float*)d_in[3];
    const float* b1   = (const float*)d_in[4];
    const float* W2   = (const float*)d_in[5];
    const float* b2   = (const float*)d_in[6];
    float* out = (float*)d_out;

    const int N = in_sizes[0] / C;
    const int E = in_sizes[2];
    const int NBIN = (N + G - 1) >> GSH;   // 313 for N=10000; must be <= MAXBIN

    char* ws = (char*)d_ws;
    unsigned short* P16 = (unsigned short*)ws;  ws += (size_t)N * C * sizeof(unsigned short);
    ws = (char*)(((uintptr_t)ws + 15) & ~(uintptr_t)15);
    float*    Q       = (float*)ws;     ws += (size_t)N * C * sizeof(float);
    unsigned* sorted  = (unsigned*)ws;  ws += (size_t)N * CAP * sizeof(unsigned);
    uint2*    bins    = (uint2*)ws;     ws += (size_t)NBIN * CAPB * sizeof(uint2);
    int2*     ovf     = (int2*)ws;      ws += (size_t)OVF_MAX * sizeof(int2);
    int*      cursor  = (int*)ws;       ws += (size_t)N * sizeof(int);
    int*      bin_cursor = (int*)ws;    ws += (size_t)NBIN * sizeof(int);
    int*      ovf_cnt = (int*)ws;       // adjacent to bin_cursor -> single memset

    hipMemsetAsync(bin_cursor, 0, ((size_t)NBIN + 1) * sizeof(int), stream);

    const int PBLK = (E + 256 * EPT1 - 1) / (256 * EPT1);   // 157 partition blocks
    const int PB = (N + NPB - 1) / NPB;                     // 625 pre-GEMM blocks
    fused_pre_kernel<<<PBLK + PB, 256, 0, stream>>>(x, W1, P16, Q, ei, attr,
                                                    bins, bin_cursor, ovf_cnt, ovf,
                                                    N, E, PBLK, NBIN);
    bin_scatter_kernel<<<NBIN, 256, 0, stream>>>(bins, bin_cursor, sorted, cursor,
                                                 ovf_cnt, ovf, N);
    agg_out_kernel<<<(N + 1) / 2, 256, 0, stream>>>(sorted, cursor, P16, Q, b1, W2, b2,
                                                    ovf_cnt, ovf, out, N);
}

// Round 2
// 137.252 us; speedup vs baseline: 1.1504x; 1.0415x over previous
//
#include <hip/hip_runtime.h>

#define C 128        // IN_CH == OUT_CH
#define NPB 16       // nodes per node-pre / out-GEMM block
#define CAP 128      // per-node bucket capacity (mean deg 64, 8 sigma; overflow path exists)
#define OVF_MAX 65536
#define EPT1 16      // edges per thread in partition kernel (block covers 4096 edges)
#define GSH 5        // log2(nodes per bin)
#define G (1 << GSH) // 32 nodes per bin
#define CAPB 3072    // bin capacity in entries (mean ~2045 + 64B-pad overhead + 8 sigma)
#define MAXBIN 512   // static LDS sizing; requires N <= MAXBIN*G (=16384)

__device__ __forceinline__ unsigned bf16_bits(float x) {   // round-to-nearest-even
    unsigned u = __float_as_uint(x);
    u += 0x7FFFu + ((u >> 16) & 1u);
    return u >> 16;
}

// Heterogeneous kernel: blocks [0, PBLK) partition edges into coarse bins (32
// nodes/bin) with LDS histograms + 64B-aligned per-block runs (coalesced,
// XCD-private line ownership -> no partial-line write amplification).
// Blocks [PBLK, PBLK+PB) compute P = x@W1[:C] (bf16), Q = x@W1[C:] (fp32).
__global__ void fused_pre_kernel(const float* __restrict__ x, const float* __restrict__ W1,
                                 unsigned short* __restrict__ P16, float* __restrict__ Q,
                                 const int* __restrict__ ei, const float* __restrict__ attr,
                                 uint2* __restrict__ bins, int* __restrict__ bin_cursor,
                                 int* __restrict__ ovf_cnt, int2* __restrict__ ovf,
                                 int N, int E, int PBLK, int NBIN) {
    if ((int)blockIdx.x < PBLK) {
        __shared__ int hist[MAXBIN];   // pass1: counts; after reserve: global run base
        __shared__ int boff[MAXBIN];   // pass2: running offset within this block's run
        for (int i = threadIdx.x; i < NBIN; i += 256) { hist[i] = 0; boff[i] = 0; }
        __syncthreads();
        const int base = ((int)blockIdx.x * 256 + (int)threadIdx.x) * EPT1;
        const int rem = (base < E) ? min(EPT1, E - base) : 0;
        const bool vec = (rem == EPT1) && ((E & 3) == 0);
        // ---- pass 1: LDS histogram of destination bins ----
        if (vec) {
#pragma unroll
            for (int j0 = 0; j0 < EPT1; j0 += 4) {
                const int4 c = *(const int4*)(ei + (size_t)E + base + j0);
                atomicAdd(&hist[c.x >> GSH], 1);
                atomicAdd(&hist[c.y >> GSH], 1);
                atomicAdd(&hist[c.z >> GSH], 1);
                atomicAdd(&hist[c.w >> GSH], 1);
            }
        } else {
            for (int j = 0; j < rem; ++j)
                atomicAdd(&hist[ei[(size_t)E + base + j] >> GSH], 1);
        }
        __syncthreads();
        // ---- reserve a 64B-aligned run per bin; sentinel-fill the pad ----
        for (int i = threadIdx.x; i < NBIN; i += 256) {
            const int c = hist[i];
            int b = 0;
            if (c) {
                const int cp = (c + 7) & ~7;           // pad to 8 entries = 64B
                b = atomicAdd(&bin_cursor[i], cp);
                for (int k = c; k < cp; ++k)
                    if (b + k < CAPB)
                        bins[(size_t)i * CAPB + b + k] = make_uint2(0u, 0xFFFFFFFFu);
            }
            hist[i] = b;                               // repurpose as run base
        }
        __syncthreads();
        // ---- pass 2: place edges into the block's private runs ----
        if (vec) {
#pragma unroll
            for (int j0 = 0; j0 < EPT1; j0 += 4) {
                const int4 r = *(const int4*)(ei + base + j0);
                const int4 c = *(const int4*)(ei + (size_t)E + base + j0);
                const float4 a = *(const float4*)(attr + base + j0);
                const int rr[4] = {r.x, r.y, r.z, r.w};
                const int cc[4] = {c.x, c.y, c.z, c.w};
                const float aa[4] = {a.x, a.y, a.z, a.w};
#pragma unroll
                for (int j = 0; j < 4; ++j) {
                    const int bin = cc[j] >> GSH;
                    const int idx = hist[bin] + atomicAdd(&boff[bin], 1);
                    const unsigned pk = (bf16_bits(aa[j]) << 16) | (unsigned)rr[j];
                    if (idx < CAPB) {
                        bins[(size_t)bin * CAPB + idx] = make_uint2(pk, (unsigned)cc[j]);
                    } else {
                        const int o = atomicAdd(ovf_cnt, 1);
                        if (o < OVF_MAX) ovf[o] = make_int2(cc[j], (int)pk);
                    }
                }
            }
        } else {
            for (int j = 0; j < rem; ++j) {
                const int row = ei[base + j], colv = ei[(size_t)E + base + j];
                const int bin = colv >> GSH;
                const int idx = hist[bin] + atomicAdd(&boff[bin], 1);
                const unsigned pk = (bf16_bits(attr[base + j]) << 16) | (unsigned)row;
                if (idx < CAPB) {
                    bins[(size_t)bin * CAPB + idx] = make_uint2(pk, (unsigned)colv);
                } else {
                    const int o = atomicAdd(ovf_cnt, 1);
                    if (o < OVF_MAX) ovf[o] = make_int2(colv, (int)pk);
                }
            }
        }
    } else {
        // node pre-GEMM: 16 nodes/block, 256 threads (half -> P bf16, half -> Q fp32)
        __shared__ float xs[NPB][C];
        const int pb = (int)blockIdx.x - PBLK;
        const int n0 = pb * NPB;
        const int tt = threadIdx.x & (C - 1);
        const int half = threadIdx.x >> 7;
        for (int i = threadIdx.x; i < NPB * C; i += 256) {
            const int gi = n0 * C + i;
            xs[0][i] = (gi < N * C) ? x[gi] : 0.f;
        }
        __syncthreads();
        const float* __restrict__ Wb = W1 + (half ? (C * C) : 0) + tt;
        float acc[NPB] = {};
        for (int k = 0; k < C; ++k) {
            const float w = Wb[k * C];
#pragma unroll
            for (int j = 0; j < NPB; ++j)
                acc[j] = fmaf(xs[j][k], w, acc[j]);
        }
#pragma unroll
        for (int j = 0; j < NPB; ++j)
            if (n0 + j < N) {
                if (half) Q[(size_t)(n0 + j) * C + tt] = acc[j];
                else      P16[(size_t)(n0 + j) * C + tt] = (unsigned short)bf16_bits(acc[j]);
            }
    }
}

// Level-2 scatter: one block per bin. Reads the bin's entries (coalesced),
// places them into exact per-node buckets via LDS position counters. The 4B
// scattered writes land in a 16KB region owned by this block -> L2-resident,
// full-line evictions. Writes exact per-node counts into cursor (no memset).
__global__ void bin_scatter_kernel(const uint2* __restrict__ bins, const int* __restrict__ bin_cursor,
                                   unsigned* __restrict__ sorted, int* __restrict__ cursor,
                                   int* __restrict__ ovf_cnt, int2* __restrict__ ovf, int N) {
    __shared__ int off[G];
    const int b = blockIdx.x;
    const int n0 = b << GSH;
    if (threadIdx.x < G) off[threadIdx.x] = 0;
    __syncthreads();
    const int cnt = min(bin_cursor[b], CAPB);
    const uint2* __restrict__ src = bins + (size_t)b * CAPB;
    for (int i = threadIdx.x; i < cnt; i += 256) {
        const uint2 e = src[i];
        const unsigned noff = e.y - (unsigned)n0;
        if (noff < (unsigned)G) {                      // skip pad sentinels
            const int pos = atomicAdd(&off[noff], 1);
            if (pos < CAP) {
                sorted[(size_t)e.y * CAP + pos] = e.x;
            } else {
                const int o = atomicAdd(ovf_cnt, 1);
                if (o < OVF_MAX) ovf[o] = make_int2((int)e.y, (int)e.x);
            }
        }
    }
    __syncthreads();
    if (threadIdx.x < G && n0 + (int)threadIdx.x < N)
        cursor[n0 + threadIdx.x] = min(off[threadIdx.x], CAP);
}

// Aggregation: H[n] = sum_edges relu(a * P16[row] + Q[n] + b1). 2 nodes per
// 256-thread block. Edge list staged in LDS (kills the global pointer-chase);
// 16 lanes x 8 channels per edge, P16 row gathered as uint4 (16B/lane).
// W2 GEMM moved to its own kernel for W2 reuse.
__global__ void agg_kernel(const unsigned* __restrict__ sorted, const int* __restrict__ cursor,
                           const unsigned short* __restrict__ P16, const float* __restrict__ Q,
                           const float* __restrict__ b1,
                           const int* __restrict__ ovf_cnt, const int2* __restrict__ ovf,
                           float* __restrict__ H, int* __restrict__ degw, int N) {
    __shared__ unsigned ebuf[2][CAP];
    __shared__ float4 red[2][8][32];
    const int t = threadIdx.x;
    const int j = t >> 7;          // node within block
    const int tl = t & 127;        // thread within node
    const int grp = tl >> 4;       // 8 edge-slices per node
    const int ch8 = t & 15;        // 16 lanes, 8 channels each
    const int n = blockIdx.x * 2 + j;

    int deg = 0, cnt = 0, mcnt = 0;
    if (n < N) {
        deg = cursor[n];
        cnt = min(deg, CAP);
        for (int i = tl; i < cnt; i += 128)
            ebuf[j][i] = sorted[(size_t)n * CAP + i];
    }
    __syncthreads();

    float4 acc0 = make_float4(0.f, 0.f, 0.f, 0.f);
    float4 acc1 = acc0;
    if (n < N) {
        const float4 qlo = *(const float4*)(Q + (size_t)n * C + (ch8 << 3));
        const float4 qhi = *(const float4*)(Q + (size_t)n * C + (ch8 << 3) + 4);
        const float4 blo = *(const float4*)(b1 + (ch8 << 3));
        const float4 bhi = *(const float4*)(b1 + (ch8 << 3) + 4);
        const float4 qb0 = make_float4(qlo.x + blo.x, qlo.y + blo.y, qlo.z + blo.z, qlo.w + blo.w);
        const float4 qb1 = make_float4(qhi.x + bhi.x, qhi.y + bhi.y, qhi.z + bhi.z, qhi.w + bhi.w);
        const int chunk = (cnt + 7) >> 3;
        const int s0 = min(grp * chunk, cnt);
        const int s1 = min(s0 + chunk, cnt);
        int i = s0;
        for (; i + 2 <= s1; i += 2) {
            const unsigned e0 = ebuf[j][i], e1 = ebuf[j][i + 1];
            const uint4 p0 = *(const uint4*)(P16 + (((size_t)(e0 & 0xFFFFu)) << 7) + (ch8 << 3));
            const uint4 p1 = *(const uint4*)(P16 + (((size_t)(e1 & 0xFFFFu)) << 7) + (ch8 << 3));
            const float a0 = __uint_as_float(e0 & 0xFFFF0000u);
            const float a1 = __uint_as_float(e1 & 0xFFFF0000u);
            acc0.x += fmaxf(fmaf(a0, __uint_as_float(p0.x << 16),         qb0.x), 0.f)
                    + fmaxf(fmaf(a1, __uint_as_float(p1.x << 16),         qb0.x), 0.f);
            acc0.y += fmaxf(fmaf(a0, __uint_as_float(p0.x & 0xFFFF0000u), qb0.y), 0.f)
                    + fmaxf(fmaf(a1, __uint_as_float(p1.x & 0xFFFF0000u), qb0.y), 0.f);
            acc0.z += fmaxf(fmaf(a0, __uint_as_float(p0.y << 16),         qb0.z), 0.f)
                    + fmaxf(fmaf(a1, __uint_as_float(p1.y << 16),         qb0.z), 0.f);
            acc0.w += fmaxf(fmaf(a0, __uint_as_float(p0.y & 0xFFFF0000u), qb0.w), 0.f)
                    + fmaxf(fmaf(a1, __uint_as_float(p1.y & 0xFFFF0000u), qb0.w), 0.f);
            acc1.x += fmaxf(fmaf(a0, __uint_as_float(p0.z << 16),         qb1.x), 0.f)
                    + fmaxf(fmaf(a1, __uint_as_float(p1.z << 16),         qb1.x), 0.f);
            acc1.y += fmaxf(fmaf(a0, __uint_as_float(p0.z & 0xFFFF0000u), qb1.y), 0.f)
                    + fmaxf(fmaf(a1, __uint_as_float(p1.z & 0xFFFF0000u), qb1.y), 0.f);
            acc1.z += fmaxf(fmaf(a0, __uint_as_float(p0.w << 16),         qb1.z), 0.f)
                    + fmaxf(fmaf(a1, __uint_as_float(p1.w << 16),         qb1.z), 0.f);
            acc1.w += fmaxf(fmaf(a0, __uint_as_float(p0.w & 0xFFFF0000u), qb1.w), 0.f)
                    + fmaxf(fmaf(a1, __uint_as_float(p1.w & 0xFFFF0000u), qb1.w), 0.f);
        }
        for (; i < s1; ++i) {
            const unsigned e0 = ebuf[j][i];
            const uint4 p0 = *(const uint4*)(P16 + (((size_t)(e0 & 0xFFFFu)) << 7) + (ch8 << 3));
            const float a0 = __uint_as_float(e0 & 0xFFFF0000u);
            acc0.x += fmaxf(fmaf(a0, __uint_as_float(p0.x << 16),         qb0.x), 0.f);
            acc0.y += fmaxf(fmaf(a0, __uint_as_float(p0.x & 0xFFFF0000u), qb0.y), 0.f);
            acc0.z += fmaxf(fmaf(a0, __uint_as_float(p0.y << 16),         qb0.z), 0.f);
            acc0.w += fmaxf(fmaf(a0, __uint_as_float(p0.y & 0xFFFF0000u), qb0.w), 0.f);
            acc1.x += fmaxf(fmaf(a0, __uint_as_float(p0.z << 16),         qb1.x), 0.f);
            acc1.y += fmaxf(fmaf(a0, __uint_as_float(p0.z & 0xFFFF0000u), qb1.y), 0.f);
            acc1.z += fmaxf(fmaf(a0, __uint_as_float(p0.w << 16),         qb1.z), 0.f);
            acc1.w += fmaxf(fmaf(a0, __uint_as_float(p0.w & 0xFFFF0000u), qb1.w), 0.f);
        }
        if (grp == 0) {   // overflow entries (essentially never populated)
            const int oc = min(*ovf_cnt, OVF_MAX);
            for (int o = 0; o < oc; ++o) {
                const int2 v = ovf[o];
                if (v.x == n) {
                    ++mcnt;
                    const unsigned u = (unsigned)v.y;
                    const uint4 p0 = *(const uint4*)(P16 + (((size_t)(u & 0xFFFFu)) << 7) + (ch8 << 3));
                    const float a0 = __uint_as_float(u & 0xFFFF0000u);
                    acc0.x += fmaxf(fmaf(a0, __uint_as_float(p0.x << 16),         qb0.x), 0.f);
                    acc0.y += fmaxf(fmaf(a0, __uint_as_float(p0.x & 0xFFFF0000u), qb0.y), 0.f);
                    acc0.z += fmaxf(fmaf(a0, __uint_as_float(p0.y << 16),         qb0.z), 0.f);
                    acc0.w += fmaxf(fmaf(a0, __uint_as_float(p0.y & 0xFFFF0000u), qb0.w), 0.f);
                    acc1.x += fmaxf(fmaf(a0, __uint_as_float(p0.z << 16),         qb1.x), 0.f);
                    acc1.y += fmaxf(fmaf(a0, __uint_as_float(p0.z & 0xFFFF0000u), qb1.y), 0.f);
                    acc1.z += fmaxf(fmaf(a0, __uint_as_float(p0.w << 16),         qb1.z), 0.f);
                    acc1.w += fmaxf(fmaf(a0, __uint_as_float(p0.w & 0xFFFF0000u), qb1.w), 0.f);
                }
            }
        }
    }
    red[j][grp][(ch8 << 1)]     = acc0;
    red[j][grp][(ch8 << 1) | 1] = acc1;
    __syncthreads();
    if (n < N) {
        if (tl == 0) degw[n] = deg + mcnt;             // tl==0 is in grp 0
        if (tl < 32) {
            float4 s = red[j][0][tl];
#pragma unroll
            for (int g = 1; g < 8; ++g) {
                const float4 r = red[j][g][tl];
                s.x += r.x; s.y += r.y; s.z += r.z; s.w += r.w;
            }
            *(float4*)(H + (size_t)n * C + (tl << 2)) = s;
        }
    }
}

// Output GEMM: out = H @ W2 + deg * b2. 16 nodes/block; W2 read once per block
// (64KB) -> 625 blocks x 64KB = 40MB L2 traffic (vs 320MB when fused per-2-nodes).
__global__ void out_gemm_kernel(const float* __restrict__ H, const float* __restrict__ W2,
                                const float* __restrict__ b2, const int* __restrict__ degw,
                                float* __restrict__ out, int N) {
    __shared__ float hsm[NPB][C];
    const int n0 = (int)blockIdx.x * NPB;
    const int col = threadIdx.x & (C - 1);
    const int half = threadIdx.x >> 7;                 // 8 nodes each
    for (int i = threadIdx.x; i < NPB * C; i += 256) {
        const int gi = n0 * C + i;
        hsm[0][i] = (gi < N * C) ? H[gi] : 0.f;
    }
    __syncthreads();
    float acc[8] = {};
    for (int k = 0; k < C; ++k) {
        const float w = W2[k * C + col];
#pragma unroll
        for (int j = 0; j < 8; ++j)
            acc[j] = fmaf(hsm[half * 8 + j][k], w, acc[j]);
    }
    const float bv = b2[col];
#pragma unroll
    for (int j = 0; j < 8; ++j) {
        const int n = n0 + half * 8 + j;
        if (n < N) out[(size_t)n * C + col] = fmaf((float)degw[n], bv, acc[j]);
    }
}

extern "C" void kernel_launch(void* const* d_in, const int* in_sizes, int n_in,
                              void* d_out, int out_size, void* d_ws, size_t ws_size,
                              hipStream_t stream) {
    const float* x    = (const float*)d_in[0];
    const int*   ei   = (const int*)d_in[1];
    const float* attr = (const float*)d_in[2];
    const float* W1   = (const float*)d_in[3];
    const float* b1   = (const float*)d_in[4];
    const float* W2   = (const float*)d_in[5];
    const float* b2   = (const float*)d_in[6];
    float* out = (float*)d_out;

    const int N = in_sizes[0] / C;
    const int E = in_sizes[2];
    const int NBIN = (N + G - 1) >> GSH;   // 313 for N=10000; must be <= MAXBIN

    char* ws = (char*)d_ws;
    unsigned short* P16 = (unsigned short*)ws;  ws += (size_t)N * C * sizeof(unsigned short);
    ws = (char*)(((uintptr_t)ws + 15) & ~(uintptr_t)15);
    float*    Q       = (float*)ws;     ws += (size_t)N * C * sizeof(float);
    float*    H       = (float*)ws;     ws += (size_t)N * C * sizeof(float);
    unsigned* sorted  = (unsigned*)ws;  ws += (size_t)N * CAP * sizeof(unsigned);
    uint2*    bins    = (uint2*)ws;     ws += (size_t)NBIN * CAPB * sizeof(uint2);
    int2*     ovf     = (int2*)ws;      ws += (size_t)OVF_MAX * sizeof(int2);
    int*      cursor  = (int*)ws;       ws += (size_t)N * sizeof(int);
    int*      degw    = (int*)ws;       ws += (size_t)N * sizeof(int);
    int*      bin_cursor = (int*)ws;    ws += (size_t)NBIN * sizeof(int);
    int*      ovf_cnt = (int*)ws;       // adjacent to bin_cursor -> single memset

    hipMemsetAsync(bin_cursor, 0, ((size_t)NBIN + 1) * sizeof(int), stream);

    const int PBLK = (E + 256 * EPT1 - 1) / (256 * EPT1);   // 157 partition blocks
    const int PB = (N + NPB - 1) / NPB;                     // 625 pre-GEMM blocks
    fused_pre_kernel<<<PBLK + PB, 256, 0, stream>>>(x, W1, P16, Q, ei, attr,
                                                    bins, bin_cursor, ovf_cnt, ovf,
                                                    N, E, PBLK, NBIN);
    bin_scatter_kernel<<<NBIN, 256, 0, stream>>>(bins, bin_cursor, sorted, cursor,
                                                 ovf_cnt, ovf, N);
    agg_kernel<<<(N + 1) / 2, 256, 0, stream>>>(sorted, cursor, P16, Q, b1,
                                                ovf_cnt, ovf, H, degw, N);
    out_gemm_kernel<<<(N + NPB - 1) / NPB, 256, 0, stream>>>(H, W2, b2, degw, out, N);
}

// Round 3
// 131.815 us; speedup vs baseline: 1.1979x; 1.0412x over previous
//
#include <hip/hip_runtime.h>

#define C 128        // IN_CH == OUT_CH
#define NPB 16       // nodes per node-pre block
#define CAP 128      // per-node LDS bucket capacity (mean deg 64, 8 sigma; overflow path exists)
#define OVF_MAX 65536
#define EPT1 32      // edges per thread in partition kernel (block covers 8192 edges)
#define GSH 4        // log2(nodes per bin)
#define G (1 << GSH) // 16 nodes per bin
#define CAPB 1792    // bin capacity in entries (mean ~1024 + run-pad overhead + slack; ovf path)
#define MAXBIN 1024  // static LDS sizing; requires NBIN <= MAXBIN
#define BCS 16       // bin_cursor stride in ints: one counter per 64B line

__device__ __forceinline__ unsigned bf16_bits(float x) {   // round-to-nearest-even
    unsigned u = __float_as_uint(x);
    u += 0x7FFFu + ((u >> 16) & 1u);
    return u >> 16;
}

// Heterogeneous kernel: blocks [0, PBLK) partition edges into coarse bins (16
// nodes/bin) with LDS histograms + 64B-aligned per-block runs (coalesced,
// XCD-private line ownership -> no partial-line write amplification).
// Blocks [PBLK, PBLK+PB) compute P = x@W1[:C] (bf16), Q = x@W1[C:] (fp32).
__global__ void fused_pre_kernel(const float* __restrict__ x, const float* __restrict__ W1,
                                 unsigned short* __restrict__ P16, float* __restrict__ Q,
                                 const int* __restrict__ ei, const float* __restrict__ attr,
                                 uint2* __restrict__ bins, int* __restrict__ bin_cursor,
                                 int* __restrict__ ovf_cnt, int2* __restrict__ ovf,
                                 int N, int E, int PBLK, int NBIN) {
    if ((int)blockIdx.x < PBLK) {
        __shared__ int hist[MAXBIN];   // pass1: counts; after reserve: global run base
        __shared__ int boff[MAXBIN];   // pass2: running offset within this block's run
        for (int i = threadIdx.x; i < NBIN; i += 256) { hist[i] = 0; boff[i] = 0; }
        __syncthreads();
        const int base = ((int)blockIdx.x * 256 + (int)threadIdx.x) * EPT1;
        const int rem = (base < E) ? min(EPT1, E - base) : 0;
        const bool vec = (rem == EPT1) && ((E & 3) == 0);
        // ---- pass 1: LDS histogram of destination bins ----
        if (vec) {
#pragma unroll
            for (int j0 = 0; j0 < EPT1; j0 += 4) {
                const int4 c = *(const int4*)(ei + (size_t)E + base + j0);
                atomicAdd(&hist[c.x >> GSH], 1);
                atomicAdd(&hist[c.y >> GSH], 1);
                atomicAdd(&hist[c.z >> GSH], 1);
                atomicAdd(&hist[c.w >> GSH], 1);
            }
        } else {
            for (int j = 0; j < rem; ++j)
                atomicAdd(&hist[ei[(size_t)E + base + j] >> GSH], 1);
        }
        __syncthreads();
        // ---- reserve a 64B-aligned run per bin; sentinel-fill the pad ----
        for (int i = threadIdx.x; i < NBIN; i += 256) {
            const int c = hist[i];
            int b = 0;
            if (c) {
                const int cp = (c + 7) & ~7;           // pad to 8 entries = 64B
                b = atomicAdd(&bin_cursor[i * BCS], cp);
                for (int k = c; k < cp; ++k)
                    if (b + k < CAPB)
                        bins[(size_t)i * CAPB + b + k] = make_uint2(0u, 0xFFFFFFFFu);
            }
            hist[i] = b;                               // repurpose as run base
        }
        __syncthreads();
        // ---- pass 2: place edges into the block's private runs ----
        if (vec) {
#pragma unroll
            for (int j0 = 0; j0 < EPT1; j0 += 4) {
                const int4 r = *(const int4*)(ei + base + j0);
                const int4 c = *(const int4*)(ei + (size_t)E + base + j0);
                const float4 a = *(const float4*)(attr + base + j0);
                const int rr[4] = {r.x, r.y, r.z, r.w};
                const int cc[4] = {c.x, c.y, c.z, c.w};
                const float aa[4] = {a.x, a.y, a.z, a.w};
#pragma unroll
                for (int j = 0; j < 4; ++j) {
                    const int bin = cc[j] >> GSH;
                    const int idx = hist[bin] + atomicAdd(&boff[bin], 1);
                    const unsigned pk = (bf16_bits(aa[j]) << 16) | (unsigned)rr[j];
                    if (idx < CAPB) {
                        bins[(size_t)bin * CAPB + idx] = make_uint2(pk, (unsigned)cc[j]);
                    } else {
                        const int o = atomicAdd(ovf_cnt, 1);
                        if (o < OVF_MAX) ovf[o] = make_int2(cc[j], (int)pk);
                    }
                }
            }
        } else {
            for (int j = 0; j < rem; ++j) {
                const int row = ei[base + j], colv = ei[(size_t)E + base + j];
                const int bin = colv >> GSH;
                const int idx = hist[bin] + atomicAdd(&boff[bin], 1);
                const unsigned pk = (bf16_bits(attr[base + j]) << 16) | (unsigned)row;
                if (idx < CAPB) {
                    bins[(size_t)bin * CAPB + idx] = make_uint2(pk, (unsigned)colv);
                } else {
                    const int o = atomicAdd(ovf_cnt, 1);
                    if (o < OVF_MAX) ovf[o] = make_int2(colv, (int)pk);
                }
            }
        }
    } else {
        // node pre-GEMM: 16 nodes/block, 256 threads (half -> P bf16, half -> Q fp32)
        __shared__ float xs[NPB][C];
        const int pb = (int)blockIdx.x - PBLK;
        const int n0 = pb * NPB;
        const int tt = threadIdx.x & (C - 1);
        const int half = threadIdx.x >> 7;
        for (int i = threadIdx.x; i < NPB * C; i += 256) {
            const int gi = n0 * C + i;
            xs[0][i] = (gi < N * C) ? x[gi] : 0.f;
        }
        __syncthreads();
        const float* __restrict__ Wb = W1 + (half ? (C * C) : 0) + tt;
        float acc[NPB] = {};
        for (int k = 0; k < C; ++k) {
            const float w = Wb[k * C];
#pragma unroll
            for (int j = 0; j < NPB; ++j)
                acc[j] = fmaf(xs[j][k], w, acc[j]);
        }
#pragma unroll
        for (int j = 0; j < NPB; ++j)
            if (n0 + j < N) {
                if (half) Q[(size_t)(n0 + j) * C + tt] = acc[j];
                else      P16[(size_t)(n0 + j) * C + tt] = (unsigned short)bf16_bits(acc[j]);
            }
    }
}

// Merged scatter + aggregation + output GEMM. One block per bin (16 nodes).
// Phase 1: stream bin entries (coalesced) into per-node LDS buckets via LDS
//          position counters (no `sorted` global round-trip).
// Phase 2: one 16-lane group per node; each lane owns 8 channels; 4-deep-ILP
//          uint4 P16 gathers; H = sum relu(a*P + Q + b1) accumulated fully in
//          registers (no slice reduce), then written into the SAME LDS (bucket
//          row g is dead once group g finishes reading it).
// Phase 3: out = H @ W2 + deg*b2 from the LDS H tile (float4 ds reads).
// ovf correctness: entries for node n are appended only by K1 (pre-launch) or
// by n's own block before its barrier -> visible to the scan that needs them.
__global__ void bin_agg_out_kernel(const uint2* __restrict__ bins, const int* __restrict__ bin_cursor,
                                   const unsigned short* __restrict__ P16, const float* __restrict__ Q,
                                   const float* __restrict__ b1, const float* __restrict__ W2,
                                   const float* __restrict__ b2,
                                   int* __restrict__ ovf_cnt, int2* __restrict__ ovf,
                                   float* __restrict__ out, int N) {
    __shared__ unsigned smem[G][C];   // phase1/2: buckets; phase3: H tile (floats)
    __shared__ int off[G];
    float* __restrict__ smemf = (float*)&smem[0][0];
    const int t = threadIdx.x;
    const int b = blockIdx.x;
    const int n0 = b << GSH;
    if (t < G) off[t] = 0;
    __syncthreads();
    // ---- phase 1: bin -> per-node LDS buckets ----
    const int cnt = min(bin_cursor[b * BCS], CAPB);
    const uint2* __restrict__ src = bins + (size_t)b * CAPB;
    for (int i = t; i < cnt; i += 256) {
        const uint2 e = src[i];
        const unsigned noff = e.y - (unsigned)n0;
        if (noff < (unsigned)G) {                      // skip run-pad sentinels
            const int pos = atomicAdd(&off[noff], 1);
            if (pos < CAP) {
                smem[noff][pos] = e.x;
            } else {
                const int o = atomicAdd(ovf_cnt, 1);
                if (o < OVF_MAX) ovf[o] = make_int2((int)e.y, (int)e.x);
            }
        }
    }
    __syncthreads();
    // ---- phase 2: per-node aggregation, 16 lanes x 8 channels ----
    const int g = t >> 4;
    const int ch8 = t & 15;
    const int n = n0 + g;
#define PROC(ew, p, qb0, qb1)                                                            \
    {                                                                                    \
        const float a_ = __uint_as_float((ew) & 0xFFFF0000u);                            \
        acc0.x += fmaxf(fmaf(a_, __uint_as_float((p).x << 16),         qb0.x), 0.f);     \
        acc0.y += fmaxf(fmaf(a_, __uint_as_float((p).x & 0xFFFF0000u), qb0.y), 0.f);     \
        acc0.z += fmaxf(fmaf(a_, __uint_as_float((p).y << 16),         qb0.z), 0.f);     \
        acc0.w += fmaxf(fmaf(a_, __uint_as_float((p).y & 0xFFFF0000u), qb0.w), 0.f);     \
        acc1.x += fmaxf(fmaf(a_, __uint_as_float((p).z << 16),         qb1.x), 0.f);     \
        acc1.y += fmaxf(fmaf(a_, __uint_as_float((p).z & 0xFFFF0000u), qb1.y), 0.f);     \
        acc1.z += fmaxf(fmaf(a_, __uint_as_float((p).w << 16),         qb1.z), 0.f);     \
        acc1.w += fmaxf(fmaf(a_, __uint_as_float((p).w & 0xFFFF0000u), qb1.w), 0.f);     \
    }
    float4 acc0 = make_float4(0.f, 0.f, 0.f, 0.f);
    float4 acc1 = acc0;
    int degp = 0, mcnt = 0;
    if (n < N) {
        degp = min(off[g], CAP);
        const float4 qlo = *(const float4*)(Q + (size_t)n * C + (ch8 << 3));
        const float4 qhi = *(const float4*)(Q + (size_t)n * C + (ch8 << 3) + 4);
        const float4 blo = *(const float4*)(b1 + (ch8 << 3));
        const float4 bhi = *(const float4*)(b1 + (ch8 << 3) + 4);
        const float4 qb0 = make_float4(qlo.x + blo.x, qlo.y + blo.y, qlo.z + blo.z, qlo.w + blo.w);
        const float4 qb1 = make_float4(qhi.x + bhi.x, qhi.y + bhi.y, qhi.z + bhi.z, qhi.w + bhi.w);
        int i = 0;
        for (; i + 4 <= degp; i += 4) {
            const uint4 e4 = *(const uint4*)(&smem[g][i]);   // broadcast: 4 edges
            const uint4 p0 = *(const uint4*)(P16 + (((size_t)(e4.x & 0xFFFFu)) << 7) + (ch8 << 3));
            const uint4 p1 = *(const uint4*)(P16 + (((size_t)(e4.y & 0xFFFFu)) << 7) + (ch8 << 3));
            const uint4 p2 = *(const uint4*)(P16 + (((size_t)(e4.z & 0xFFFFu)) << 7) + (ch8 << 3));
            const uint4 p3 = *(const uint4*)(P16 + (((size_t)(e4.w & 0xFFFFu)) << 7) + (ch8 << 3));
            PROC(e4.x, p0, qb0, qb1);
            PROC(e4.y, p1, qb0, qb1);
            PROC(e4.z, p2, qb0, qb1);
            PROC(e4.w, p3, qb0, qb1);
        }
        for (; i < degp; ++i) {
            const unsigned ew = smem[g][i];
            const uint4 p = *(const uint4*)(P16 + (((size_t)(ew & 0xFFFFu)) << 7) + (ch8 << 3));
            PROC(ew, p, qb0, qb1);
        }
        // overflow entries (essentially never populated)
        const int oc = min(*ovf_cnt, OVF_MAX);
        for (int o = 0; o < oc; ++o) {
            const int2 v = ovf[o];
            if (v.x == n) {
                ++mcnt;
                const unsigned ew = (unsigned)v.y;
                const uint4 p = *(const uint4*)(P16 + (((size_t)(ew & 0xFFFFu)) << 7) + (ch8 << 3));
                PROC(ew, p, qb0, qb1);
            }
        }
        // bucket row g fully consumed -> overwrite in place with H row g
        *(float4*)(smemf + g * C + (ch8 << 3))     = acc0;
        *(float4*)(smemf + g * C + (ch8 << 3) + 4) = acc1;
        if (ch8 == 0) off[g] = degp + mcnt;            // final degree for b2 term
    }
#undef PROC
    __syncthreads();
    // ---- phase 3: out = H @ W2 + deg*b2 (8 nodes per half, float4 ds reads) ----
    const int col = t & (C - 1);
    const int half = t >> 7;
    float acc[8] = {};
    for (int k = 0; k < C; k += 4) {
        const float w0 = W2[(k + 0) * C + col];
        const float w1 = W2[(k + 1) * C + col];
        const float w2v = W2[(k + 2) * C + col];
        const float w3 = W2[(k + 3) * C + col];
#pragma unroll
        for (int j = 0; j < 8; ++j) {
            const float4 h4 = *(const float4*)(smemf + (half * 8 + j) * C + k);
            acc[j] = fmaf(h4.x, w0, fmaf(h4.y, w1, fmaf(h4.z, w2v, fmaf(h4.w, w3, acc[j]))));
        }
    }
    const float bv = b2[col];
#pragma unroll
    for (int j = 0; j < 8; ++j) {
        const int n2 = n0 + half * 8 + j;
        if (n2 < N) out[(size_t)n2 * C + col] = fmaf((float)off[half * 8 + j], bv, acc[j]);
    }
}

extern "C" void kernel_launch(void* const* d_in, const int* in_sizes, int n_in,
                              void* d_out, int out_size, void* d_ws, size_t ws_size,
                              hipStream_t stream) {
    const float* x    = (const float*)d_in[0];
    const int*   ei   = (const int*)d_in[1];
    const float* attr = (const float*)d_in[2];
    const float* W1   = (const float*)d_in[3];
    const float* b1   = (const float*)d_in[4];
    const float* W2   = (const float*)d_in[5];
    const float* b2   = (const float*)d_in[6];
    float* out = (float*)d_out;

    const int N = in_sizes[0] / C;
    const int E = in_sizes[2];
    const int NBIN = (N + G - 1) >> GSH;   // 625 for N=10000; must be <= MAXBIN

    char* ws = (char*)d_ws;
    unsigned short* P16 = (unsigned short*)ws;  ws += (size_t)N * C * sizeof(unsigned short);
    ws = (char*)(((uintptr_t)ws + 15) & ~(uintptr_t)15);
    float*    Q       = (float*)ws;     ws += (size_t)N * C * sizeof(float);
    uint2*    bins    = (uint2*)ws;     ws += (size_t)NBIN * CAPB * sizeof(uint2);
    int2*     ovf     = (int2*)ws;      ws += (size_t)OVF_MAX * sizeof(int2);
    int*      bin_cursor = (int*)ws;    ws += (size_t)NBIN * BCS * sizeof(int);
    int*      ovf_cnt = (int*)ws;       // adjacent to bin_cursor -> single memset

    hipMemsetAsync(bin_cursor, 0, ((size_t)NBIN * BCS + 1) * sizeof(int), stream);

    const int PBLK = (E + 256 * EPT1 - 1) / (256 * EPT1);   // 79 partition blocks
    const int PB = (N + NPB - 1) / NPB;                     // 625 pre-GEMM blocks
    fused_pre_kernel<<<PBLK + PB, 256, 0, stream>>>(x, W1, P16, Q, ei, attr,
                                                    bins, bin_cursor, ovf_cnt, ovf,
                                                    N, E, PBLK, NBIN);
    bin_agg_out_kernel<<<NBIN, 256, 0, stream>>>(bins, bin_cursor, P16, Q, b1, W2, b2,
                                                 ovf_cnt, ovf, out, N);
}

// Round 4
// 131.522 us; speedup vs baseline: 1.2005x; 1.0022x over previous
//
#include <hip/hip_runtime.h>

#define C 128        // IN_CH == OUT_CH
#define NPB 16       // nodes per node-pre block
#define CAP 128      // per-node LDS bucket capacity (mean deg 64, 8 sigma; overflow path exists)
#define OVF_MAX 65536
#define EPT1 32      // edges per thread in partition kernel (block covers 8192 edges)
#define GSH 4        // log2(nodes per bin)
#define G (1 << GSH) // 16 nodes per bin
#define CAPB 1792    // bin capacity in entries (mean ~1024 + run-pad overhead + slack; ovf path)
#define MAXBIN 1024  // static LDS sizing; requires NBIN <= MAXBIN
#define BCS 16       // bin_cursor stride in ints: one counter per 64B line

__device__ __forceinline__ unsigned bf16_bits(float x) {   // round-to-nearest-even
    unsigned u = __float_as_uint(x);
    u += 0x7FFFu + ((u >> 16) & 1u);
    return u >> 16;
}

// Heterogeneous kernel: blocks [0, PBLK) partition edges into coarse bins (16
// nodes/bin) with LDS histograms + 64B-aligned per-block runs (coalesced,
// XCD-private line ownership -> no partial-line write amplification).
// Blocks [PBLK, PBLK+PB) compute P = x@W1[:C] (bf16), Q = x@W1[C:] (fp32).
// Pre-GEMM tiling: 4 nodes x 4 cols per thread -> ds_read_b128 broadcasts,
// 16 FMA per LDS inst (was 1 per ds_read_b32 -> LDS-pipe-bound at ~10 waves/CU).
__global__ void fused_pre_kernel(const float* __restrict__ x, const float* __restrict__ W1,
                                 unsigned short* __restrict__ P16, float* __restrict__ Q,
                                 const int* __restrict__ ei, const float* __restrict__ attr,
                                 uint2* __restrict__ bins, int* __restrict__ bin_cursor,
                                 int* __restrict__ ovf_cnt, int2* __restrict__ ovf,
                                 int N, int E, int PBLK, int NBIN) {
    if ((int)blockIdx.x < PBLK) {
        __shared__ int hist[MAXBIN];   // pass1: counts; after reserve: global run base
        __shared__ int boff[MAXBIN];   // pass2: running offset within this block's run
        for (int i = threadIdx.x; i < NBIN; i += 256) { hist[i] = 0; boff[i] = 0; }
        __syncthreads();
        const int base = ((int)blockIdx.x * 256 + (int)threadIdx.x) * EPT1;
        const int rem = (base < E) ? min(EPT1, E - base) : 0;
        const bool vec = (rem == EPT1) && ((E & 3) == 0);
        // ---- pass 1: LDS histogram of destination bins ----
        if (vec) {
#pragma unroll
            for (int j0 = 0; j0 < EPT1; j0 += 4) {
                const int4 c = *(const int4*)(ei + (size_t)E + base + j0);
                atomicAdd(&hist[c.x >> GSH], 1);
                atomicAdd(&hist[c.y >> GSH], 1);
                atomicAdd(&hist[c.z >> GSH], 1);
                atomicAdd(&hist[c.w >> GSH], 1);
            }
        } else {
            for (int j = 0; j < rem; ++j)
                atomicAdd(&hist[ei[(size_t)E + base + j] >> GSH], 1);
        }
        __syncthreads();
        // ---- reserve a 64B-aligned run per bin; sentinel-fill the pad ----
        for (int i = threadIdx.x; i < NBIN; i += 256) {
            const int c = hist[i];
            int b = 0;
            if (c) {
                const int cp = (c + 7) & ~7;           // pad to 8 entries = 64B
                b = atomicAdd(&bin_cursor[i * BCS], cp);
                for (int k = c; k < cp; ++k)
                    if (b + k < CAPB)
                        bins[(size_t)i * CAPB + b + k] = make_uint2(0u, 0xFFFFFFFFu);
            }
            hist[i] = b;                               // repurpose as run base
        }
        __syncthreads();
        // ---- pass 2: place edges into the block's private runs ----
        if (vec) {
#pragma unroll
            for (int j0 = 0; j0 < EPT1; j0 += 4) {
                const int4 r = *(const int4*)(ei + base + j0);
                const int4 c = *(const int4*)(ei + (size_t)E + base + j0);
                const float4 a = *(const float4*)(attr + base + j0);
                const int rr[4] = {r.x, r.y, r.z, r.w};
                const int cc[4] = {c.x, c.y, c.z, c.w};
                const float aa[4] = {a.x, a.y, a.z, a.w};
#pragma unroll
                for (int j = 0; j < 4; ++j) {
                    const int bin = cc[j] >> GSH;
                    const int idx = hist[bin] + atomicAdd(&boff[bin], 1);
                    const unsigned pk = (bf16_bits(aa[j]) << 16) | (unsigned)rr[j];
                    if (idx < CAPB) {
                        bins[(size_t)bin * CAPB + idx] = make_uint2(pk, (unsigned)cc[j]);
                    } else {
                        const int o = atomicAdd(ovf_cnt, 1);
                        if (o < OVF_MAX) ovf[o] = make_int2(cc[j], (int)pk);
                    }
                }
            }
        } else {
            for (int j = 0; j < rem; ++j) {
                const int row = ei[base + j], colv = ei[(size_t)E + base + j];
                const int bin = colv >> GSH;
                const int idx = hist[bin] + atomicAdd(&boff[bin], 1);
                const unsigned pk = (bf16_bits(attr[base + j]) << 16) | (unsigned)row;
                if (idx < CAPB) {
                    bins[(size_t)bin * CAPB + idx] = make_uint2(pk, (unsigned)colv);
                } else {
                    const int o = atomicAdd(ovf_cnt, 1);
                    if (o < OVF_MAX) ovf[o] = make_int2(colv, (int)pk);
                }
            }
        }
    } else {
        // node pre-GEMM: 16 nodes/block, 256 threads. Thread = (node-group jg,
        // col-group col4): 4 nodes x 4 consecutive cols of the 256-wide [P|Q].
        __shared__ float xs[NPB][C];
        const int pb = (int)blockIdx.x - PBLK;
        const int n0 = pb * NPB;
        for (int i = threadIdx.x; i < NPB * C; i += 256) {
            const int gi = n0 * C + i;
            xs[0][i] = (gi < N * C) ? x[gi] : 0.f;
        }
        __syncthreads();
        const int col4 = threadIdx.x & 63;             // 64 col-groups
        const int jg   = threadIdx.x >> 6;             // wave index = node group
        const bool isQ = col4 >= 32;
        const int c0   = (isQ ? (col4 - 32) : col4) << 2;
        const float* __restrict__ Wb = W1 + (isQ ? (C * C) : 0) + c0;
        float acc[4][4] = {};
        for (int k = 0; k < C; k += 4) {
            const float4 w0 = *(const float4*)(Wb + (size_t)(k + 0) * C);
            const float4 w1 = *(const float4*)(Wb + (size_t)(k + 1) * C);
            const float4 w2 = *(const float4*)(Wb + (size_t)(k + 2) * C);
            const float4 w3 = *(const float4*)(Wb + (size_t)(k + 3) * C);
#pragma unroll
            for (int j = 0; j < 4; ++j) {
                const float4 xv = *(const float4*)(&xs[jg * 4 + j][k]);   // broadcast b128
                acc[j][0] = fmaf(xv.x, w0.x, fmaf(xv.y, w1.x, fmaf(xv.z, w2.x, fmaf(xv.w, w3.x, acc[j][0]))));
                acc[j][1] = fmaf(xv.x, w0.y, fmaf(xv.y, w1.y, fmaf(xv.z, w2.y, fmaf(xv.w, w3.y, acc[j][1]))));
                acc[j][2] = fmaf(xv.x, w0.z, fmaf(xv.y, w1.z, fmaf(xv.z, w2.z, fmaf(xv.w, w3.z, acc[j][2]))));
                acc[j][3] = fmaf(xv.x, w0.w, fmaf(xv.y, w1.w, fmaf(xv.z, w2.w, fmaf(xv.w, w3.w, acc[j][3]))));
            }
        }
#pragma unroll
        for (int j = 0; j < 4; ++j) {
            const int n = n0 + jg * 4 + j;
            if (n < N) {
                if (isQ) {
                    *(float4*)(Q + (size_t)n * C + c0) =
                        make_float4(acc[j][0], acc[j][1], acc[j][2], acc[j][3]);
                } else {
                    ushort4 s;
                    s.x = (unsigned short)bf16_bits(acc[j][0]);
                    s.y = (unsigned short)bf16_bits(acc[j][1]);
                    s.z = (unsigned short)bf16_bits(acc[j][2]);
                    s.w = (unsigned short)bf16_bits(acc[j][3]);
                    *(ushort4*)(P16 + (size_t)n * C + c0) = s;
                }
            }
        }
    }
}

// Merged scatter + aggregation + output GEMM. One block per bin (16 nodes).
// Phase 1: stream bin entries (coalesced) into per-node LDS buckets via LDS
//          position counters (no `sorted` global round-trip).
// Phase 2: one 16-lane group per node; each lane owns 8 channels; 4-deep-ILP
//          uint4 P16 gathers; H = sum relu(a*P + Q + b1) accumulated fully in
//          registers (no slice reduce), then written into the SAME LDS (bucket
//          row g is dead once group g finishes reading it).
// Phase 3: out = H @ W2 + deg*b2 from the LDS H tile (float4 ds reads).
// ovf correctness: entries for node n are appended only by K1 (pre-launch) or
// by n's own block before its barrier -> visible to the scan that needs them.
__global__ void bin_agg_out_kernel(const uint2* __restrict__ bins, const int* __restrict__ bin_cursor,
                                   const unsigned short* __restrict__ P16, const float* __restrict__ Q,
                                   const float* __restrict__ b1, const float* __restrict__ W2,
                                   const float* __restrict__ b2,
                                   int* __restrict__ ovf_cnt, int2* __restrict__ ovf,
                                   float* __restrict__ out, int N) {
    __shared__ unsigned smem[G][C];   // phase1/2: buckets; phase3: H tile (floats)
    __shared__ int off[G];
    float* __restrict__ smemf = (float*)&smem[0][0];
    const int t = threadIdx.x;
    const int b = blockIdx.x;
    const int n0 = b << GSH;
    if (t < G) off[t] = 0;
    __syncthreads();
    // ---- phase 1: bin -> per-node LDS buckets ----
    const int cnt = min(bin_cursor[b * BCS], CAPB);
    const uint2* __restrict__ src = bins + (size_t)b * CAPB;
    for (int i = t; i < cnt; i += 256) {
        const uint2 e = src[i];
        const unsigned noff = e.y - (unsigned)n0;
        if (noff < (unsigned)G) {                      // skip run-pad sentinels
            const int pos = atomicAdd(&off[noff], 1);
            if (pos < CAP) {
                smem[noff][pos] = e.x;
            } else {
                const int o = atomicAdd(ovf_cnt, 1);
                if (o < OVF_MAX) ovf[o] = make_int2((int)e.y, (int)e.x);
            }
        }
    }
    __syncthreads();
    // ---- phase 2: per-node aggregation, 16 lanes x 8 channels ----
    const int g = t >> 4;
    const int ch8 = t & 15;
    const int n = n0 + g;
#define PROC(ew, p, qb0, qb1)                                                            \
    {                                                                                    \
        const float a_ = __uint_as_float((ew) & 0xFFFF0000u);                            \
        acc0.x += fmaxf(fmaf(a_, __uint_as_float((p).x << 16),         qb0.x), 0.f);     \
        acc0.y += fmaxf(fmaf(a_, __uint_as_float((p).x & 0xFFFF0000u), qb0.y), 0.f);     \
        acc0.z += fmaxf(fmaf(a_, __uint_as_float((p).y << 16),         qb0.z), 0.f);     \
        acc0.w += fmaxf(fmaf(a_, __uint_as_float((p).y & 0xFFFF0000u), qb0.w), 0.f);     \
        acc1.x += fmaxf(fmaf(a_, __uint_as_float((p).z << 16),         qb1.x), 0.f);     \
        acc1.y += fmaxf(fmaf(a_, __uint_as_float((p).z & 0xFFFF0000u), qb1.y), 0.f);     \
        acc1.z += fmaxf(fmaf(a_, __uint_as_float((p).w << 16),         qb1.z), 0.f);     \
        acc1.w += fmaxf(fmaf(a_, __uint_as_float((p).w & 0xFFFF0000u), qb1.w), 0.f);     \
    }
    float4 acc0 = make_float4(0.f, 0.f, 0.f, 0.f);
    float4 acc1 = acc0;
    int degp = 0, mcnt = 0;
    if (n < N) {
        degp = min(off[g], CAP);
        const float4 qlo = *(const float4*)(Q + (size_t)n * C + (ch8 << 3));
        const float4 qhi = *(const float4*)(Q + (size_t)n * C + (ch8 << 3) + 4);
        const float4 blo = *(const float4*)(b1 + (ch8 << 3));
        const float4 bhi = *(const float4*)(b1 + (ch8 << 3) + 4);
        const float4 qb0 = make_float4(qlo.x + blo.x, qlo.y + blo.y, qlo.z + blo.z, qlo.w + blo.w);
        const float4 qb1 = make_float4(qhi.x + bhi.x, qhi.y + bhi.y, qhi.z + bhi.z, qhi.w + bhi.w);
        int i = 0;
        for (; i + 4 <= degp; i += 4) {
            const uint4 e4 = *(const uint4*)(&smem[g][i]);   // broadcast: 4 edges
            const uint4 p0 = *(const uint4*)(P16 + (((size_t)(e4.x & 0xFFFFu)) << 7) + (ch8 << 3));
            const uint4 p1 = *(const uint4*)(P16 + (((size_t)(e4.y & 0xFFFFu)) << 7) + (ch8 << 3));
            const uint4 p2 = *(const uint4*)(P16 + (((size_t)(e4.z & 0xFFFFu)) << 7) + (ch8 << 3));
            const uint4 p3 = *(const uint4*)(P16 + (((size_t)(e4.w & 0xFFFFu)) << 7) + (ch8 << 3));
            PROC(e4.x, p0, qb0, qb1);
            PROC(e4.y, p1, qb0, qb1);
            PROC(e4.z, p2, qb0, qb1);
            PROC(e4.w, p3, qb0, qb1);
        }
        for (; i < degp; ++i) {
            const unsigned ew = smem[g][i];
            const uint4 p = *(const uint4*)(P16 + (((size_t)(ew & 0xFFFFu)) << 7) + (ch8 << 3));
            PROC(ew, p, qb0, qb1);
        }
        // overflow entries (essentially never populated)
        const int oc = min(*ovf_cnt, OVF_MAX);
        for (int o = 0; o < oc; ++o) {
            const int2 v = ovf[o];
            if (v.x == n) {
                ++mcnt;
                const unsigned ew = (unsigned)v.y;
                const uint4 p = *(const uint4*)(P16 + (((size_t)(ew & 0xFFFFu)) << 7) + (ch8 << 3));
                PROC(ew, p, qb0, qb1);
            }
        }
        // bucket row g fully consumed -> overwrite in place with H row g
        *(float4*)(smemf + g * C + (ch8 << 3))     = acc0;
        *(float4*)(smemf + g * C + (ch8 << 3) + 4) = acc1;
        if (ch8 == 0) off[g] = degp + mcnt;            // final degree for b2 term
    }
#undef PROC
    __syncthreads();
    // ---- phase 3: out = H @ W2 + deg*b2 (8 nodes per half, float4 ds reads) ----
    const int col = t & (C - 1);
    const int half = t >> 7;
    float acc[8] = {};
    for (int k = 0; k < C; k += 4) {
        const float w0 = W2[(k + 0) * C + col];
        const float w1 = W2[(k + 1) * C + col];
        const float w2v = W2[(k + 2) * C + col];
        const float w3 = W2[(k + 3) * C + col];
#pragma unroll
        for (int j = 0; j < 8; ++j) {
            const float4 h4 = *(const float4*)(smemf + (half * 8 + j) * C + k);
            acc[j] = fmaf(h4.x, w0, fmaf(h4.y, w1, fmaf(h4.z, w2v, fmaf(h4.w, w3, acc[j]))));
        }
    }
    const float bv = b2[col];
#pragma unroll
    for (int j = 0; j < 8; ++j) {
        const int n2 = n0 + half * 8 + j;
        if (n2 < N) out[(size_t)n2 * C + col] = fmaf((float)off[half * 8 + j], bv, acc[j]);
    }
}

extern "C" void kernel_launch(void* const* d_in, const int* in_sizes, int n_in,
                              void* d_out, int out_size, void* d_ws, size_t ws_size,
                              hipStream_t stream) {
    const float* x    = (const float*)d_in[0];
    const int*   ei   = (const int*)d_in[1];
    const float* attr = (const float*)d_in[2];
    const float* W1   = (const float*)d_in[3];
    const float* b1   = (const float*)d_in[4];
    const float* W2   = (const float*)d_in[5];
    const float* b2   = (const float*)d_in[6];
    float* out = (float*)d_out;

    const int N = in_sizes[0] / C;
    const int E = in_sizes[2];
    const int NBIN = (N + G - 1) >> GSH;   // 625 for N=10000; must be <= MAXBIN

    char* ws = (char*)d_ws;
    unsigned short* P16 = (unsigned short*)ws;  ws += (size_t)N * C * sizeof(unsigned short);
    ws = (char*)(((uintptr_t)ws + 15) & ~(uintptr_t)15);
    float*    Q       = (float*)ws;     ws += (size_t)N * C * sizeof(float);
    uint2*    bins    = (uint2*)ws;     ws += (size_t)NBIN * CAPB * sizeof(uint2);
    int2*     ovf     = (int2*)ws;      ws += (size_t)OVF_MAX * sizeof(int2);
    int*      bin_cursor = (int*)ws;    ws += (size_t)NBIN * BCS * sizeof(int);
    int*      ovf_cnt = (int*)ws;       // adjacent to bin_cursor -> single memset

    hipMemsetAsync(bin_cursor, 0, ((size_t)NBIN * BCS + 1) * sizeof(int), stream);

    const int PBLK = (E + 256 * EPT1 - 1) / (256 * EPT1);   // 79 partition blocks
    const int PB = (N + NPB - 1) / NPB;                     // 625 pre-GEMM blocks
    fused_pre_kernel<<<PBLK + PB, 256, 0, stream>>>(x, W1, P16, Q, ei, attr,
                                                    bins, bin_cursor, ovf_cnt, ovf,
                                                    N, E, PBLK, NBIN);
    bin_agg_out_kernel<<<NBIN, 256, 0, stream>>>(bins, bin_cursor, P16, Q, b1, W2, b2,
                                                 ovf_cnt, ovf, out, N);
}